// Round 1
// baseline (407.239 us; speedup 1.0000x reference)
//
#include <hip/hip_runtime.h>

#define H 128
#define W 128
#define S 8

// out[bc, s, i, j] = sum_{u,v in [0,5)} f[s,u,v] * T[bc, i+u-sy, j+v-sx]
// with zero padding outside [0,128)^2.

__global__ __launch_bounds__(256) void shifted_conv_kernel(
    const float* __restrict__ tens,     // [256][128][128]
    const float* __restrict__ filters,  // [8][5][5]
    const int*   __restrict__ shifts,   // [8][2]
    float* __restrict__ out)            // [256][8][128][128]
{
    // Block decomposition: blockIdx.x = img * 16 + rowTile
    //   img = bc*8 + s  (0..2047), rowTile = 0..15 (8 rows each)
    int blk = blockIdx.x;
    int rowTile = blk & 15;
    int img = blk >> 4;
    int s  = img & 7;
    int bc = img >> 3;

    int sy = shifts[2 * s];
    int sx = shifts[2 * s + 1];

    // Filter taps: block-uniform -> scalar loads
    float f[25];
#pragma unroll
    for (int t = 0; t < 25; ++t) f[t] = filters[s * 25 + t];

    int tid = threadIdx.x;
    int jt = tid & 31;        // 32 threads per row, 4 outputs each
    int it = tid >> 5;        // 8 rows per block
    int i  = rowTile * 8 + it;
    int j0 = jt * 4;

    const float* Timg = tens + (size_t)bc * (H * W);

    float acc0 = 0.f, acc1 = 0.f, acc2 = 0.f, acc3 = 0.f;

#pragma unroll
    for (int u = 0; u < 5; ++u) {
        int y = i + u - sy;
        if ((unsigned)y < (unsigned)H) {
            const float* row = Timg + y * W;
            int xb = j0 - sx;
            float w[8];
#pragma unroll
            for (int k = 0; k < 8; ++k) {
                int x = xb + k;
                w[k] = ((unsigned)x < (unsigned)W) ? row[x] : 0.f;
            }
#pragma unroll
            for (int v = 0; v < 5; ++v) {
                float fv = f[u * 5 + v];
                acc0 = fmaf(fv, w[v + 0], acc0);
                acc1 = fmaf(fv, w[v + 1], acc1);
                acc2 = fmaf(fv, w[v + 2], acc2);
                acc3 = fmaf(fv, w[v + 3], acc3);
            }
        }
    }

    float4* o = (float4*)(out + (size_t)img * (H * W) + i * W + j0);
    *o = make_float4(acc0, acc1, acc2, acc3);
}

extern "C" void kernel_launch(void* const* d_in, const int* in_sizes, int n_in,
                              void* d_out, int out_size, void* d_ws, size_t ws_size,
                              hipStream_t stream) {
    const float* tens    = (const float*)d_in[0];
    const float* filters = (const float*)d_in[1];
    const int*   shifts  = (const int*)d_in[2];
    float* out = (float*)d_out;

    // 2048 images (bc*8+s) x 16 row tiles
    int blocks = 2048 * 16;
    shifted_conv_kernel<<<blocks, 256, 0, stream>>>(tens, filters, shifts, out);
}

// Round 6
// 212.967 us; speedup vs baseline: 1.9122x; 1.9122x over previous
//
#include <hip/hip_runtime.h>

#define H 128
#define W 128
#define NS 8
#define TR 8        // output rows per block
#define LR 16       // TR + 8 halo rows
#define LC 136      // W + 8 halo cols

// out[bc, s, i, j] = sum_{u,v} f[s,u,v] * T[bc, i+u-sy_s, j+v-sx_s], zero-padded.

__global__ __launch_bounds__(256) void shifted_conv_v2(
    const float* __restrict__ tens,     // [256][128][128]
    const float* __restrict__ filters,  // [8][5][5]
    const int*   __restrict__ shifts,   // [8][2]
    float* __restrict__ out)            // [256][8][128][128]
{
    __shared__ float lds[LR][LC];   // 8704 B

    int blk  = blockIdx.x;
    int tile = blk & 15;
    int bc   = blk >> 4;
    int i0   = tile * TR;

    int tid = threadIdx.x;

    // ---- stage rows y in [i0-4, i0+12), cols x in [-4, 132) as float4 slots.
    // Slot (r, c4): lds[r][c4*4 .. c4*4+4) <- global cols [4*c4-4, 4*c4);
    // c4==0 and c4==33 are pure halo -> zeros; 1..32 map to full row [0,128).
    {
        int r      = tid >> 4;        // 0..15
        int c4base = tid & 15;        // 0..15
        int y = i0 - 4 + r;
        const float4* grow = (const float4*)(tens + (size_t)bc * (H * W) + y * W);
        bool yok = (unsigned)y < (unsigned)H;
        #pragma unroll
        for (int rep = 0; rep < 3; ++rep) {
            int c4 = c4base + rep * 16;
            if (c4 < 34) {
                float4 v = make_float4(0.f, 0.f, 0.f, 0.f);
                int x4 = c4 - 1;                       // global float4 index
                if (yok && (unsigned)x4 < 32u) v = grow[x4];
                *(float4*)&lds[r][c4 * 4] = v;
            }
        }
    }
    __syncthreads();

    int it = tid >> 5;      // 0..7  (output row within tile)
    int jt = tid & 31;      // 32 threads per row
    int j0 = jt * 4;        // 4 consecutive outputs per thread

    float* obase = out + (size_t)bc * (NS * H * W) + (size_t)(i0 + it) * W + j0;

    #pragma unroll
    for (int s = 0; s < NS; ++s) {
        int sy = shifts[2 * s];
        int sx = shifts[2 * s + 1];

        float acc0 = 0.f, acc1 = 0.f, acc2 = 0.f, acc3 = 0.f;

        #pragma unroll
        for (int u = 0; u < 5; ++u) {
            // zero-expanded 9-tap filter for this (s,u): g[m] = f[u][m-4+sx]
            float g[9];
            #pragma unroll
            for (int m = 0; m < 9; ++m) {
                int v = m - 4 + sx;
                g[m] = ((unsigned)v < 5u) ? filters[s * 25 + u * 5 + v] : 0.f;
            }

            int row = it + u + 4 - sy;            // in [0,16)
            const float* rp = &lds[row][j0];      // window lds cols [j0, j0+12)
            float4 w0 = *(const float4*)(rp);
            float4 w1 = *(const float4*)(rp + 4);
            float4 w2 = *(const float4*)(rp + 8);
            float wb[12] = {w0.x, w0.y, w0.z, w0.w,
                            w1.x, w1.y, w1.z, w1.w,
                            w2.x, w2.y, w2.z, w2.w};

            #pragma unroll
            for (int m = 0; m < 9; ++m) {
                float fv = g[m];
                acc0 = fmaf(fv, wb[m + 0], acc0);
                acc1 = fmaf(fv, wb[m + 1], acc1);
                acc2 = fmaf(fv, wb[m + 2], acc2);
                acc3 = fmaf(fv, wb[m + 3], acc3);
            }
        }

        *(float4*)(obase + (size_t)s * (H * W)) = make_float4(acc0, acc1, acc2, acc3);
    }
}

extern "C" void kernel_launch(void* const* d_in, const int* in_sizes, int n_in,
                              void* d_out, int out_size, void* d_ws, size_t ws_size,
                              hipStream_t stream) {
    const float* tens    = (const float*)d_in[0];
    const float* filters = (const float*)d_in[1];
    const int*   shifts  = (const int*)d_in[2];
    float* out = (float*)d_out;

    // 256 bc images x 16 row tiles
    shifted_conv_v2<<<256 * 16, 256, 0, stream>>>(tens, filters, shifts, out);
}

// Round 7
// 178.162 us; speedup vs baseline: 2.2858x; 1.1954x over previous
//
#include <hip/hip_runtime.h>

#define H 128
#define W 128
#define NS 8
#define TR 8        // output rows per block
#define LR 16       // TR + 8 halo rows
#define LC 136      // W + 8 halo cols

// Zero-expanded tap table: Gt[dy][s][m] (m padded to 16) =
//   f[s][u][v] with u = dy-4+sy_s, v = m-4+sx_s, zero if u or v outside [0,5).
__device__ float g_gt[9 * 8 * 16];

__global__ __launch_bounds__(256) void build_gt(
    const float* __restrict__ filters,  // [8][5][5]
    const int*   __restrict__ shifts)   // [8][2]
{
    int t = blockIdx.x * 256 + threadIdx.x;
    if (t >= 9 * 8 * 16) return;
    int m  = t & 15;
    int s  = (t >> 4) & 7;
    int dy = t >> 7;
    float val = 0.f;
    if (m < 9) {
        int u = dy - 4 + shifts[2 * s];
        int v = m - 4 + shifts[2 * s + 1];
        if ((unsigned)u < 5u && (unsigned)v < 5u)
            val = filters[s * 25 + u * 5 + v];
    }
    g_gt[t] = val;
}

// out[bc, s, i, j] = sum_{u,v} f[s,u,v] * T[bc, i+u-sy_s, j+v-sx_s], zero-padded.
__global__ __launch_bounds__(256) void shifted_conv_v3(
    const float* __restrict__ tens,     // [256][128][128]
    const int*   __restrict__ shifts,   // [8][2]
    float* __restrict__ out)            // [256][8][128][128]
{
    __shared__ float lds[LR][LC];   // 8704 B

    int blk  = blockIdx.x;
    int tile = blk & 15;
    int bc   = blk >> 4;
    int i0   = tile * TR;

    int tid = threadIdx.x;

    // ---- stage rows y in [i0-4, i0+12), cols x in [-4, 132) as float4 slots.
    {
        int r      = tid >> 4;        // 0..15
        int c4base = tid & 15;        // 0..15
        int y = i0 - 4 + r;
        const float4* grow = (const float4*)(tens + (size_t)bc * (H * W) + y * W);
        bool yok = (unsigned)y < (unsigned)H;
        #pragma unroll
        for (int rep = 0; rep < 3; ++rep) {
            int c4 = c4base + rep * 16;
            if (c4 < 34) {
                float4 v = make_float4(0.f, 0.f, 0.f, 0.f);
                int x4 = c4 - 1;                       // global float4 index
                if (yok && (unsigned)x4 < 32u) v = grow[x4];
                *(float4*)&lds[r][c4 * 4] = v;
            }
        }
    }

    // Block-uniform shift rows, forced scalar.
    int sy[NS];
    #pragma unroll
    for (int s = 0; s < NS; ++s)
        sy[s] = __builtin_amdgcn_readfirstlane(shifts[2 * s]);

    __syncthreads();

    int it = tid >> 5;      // 0..7  (output row within tile)
    int jt = tid & 31;      // 32 threads per row
    int j0 = jt * 4;        // 4 consecutive outputs per thread

    float acc[NS][4];
    #pragma unroll
    for (int s = 0; s < NS; ++s)
        #pragma unroll
        for (int k = 0; k < 4; ++k) acc[s][k] = 0.f;

    const float* rp = &lds[it][j0];   // 16B-aligned (136%4==0, j0%4==0)

    #pragma unroll
    for (int dy = 0; dy < 9; ++dy) {
        // one window read per dy, shared by all 8 shifts
        float4 w0 = *(const float4*)(rp + dy * LC);
        float4 w1 = *(const float4*)(rp + dy * LC + 4);
        float4 w2 = *(const float4*)(rp + dy * LC + 8);
        float w[12] = {w0.x, w0.y, w0.z, w0.w,
                       w1.x, w1.y, w1.z, w1.w,
                       w2.x, w2.y, w2.z, w2.w};

        #pragma unroll
        for (int s = 0; s < NS; ++s) {
            // block-uniform: u = dy-4+sy_s must be a real filter row
            if ((unsigned)(dy - 4 + sy[s]) < 5u) {
                #pragma unroll
                for (int m = 0; m < 9; ++m) {
                    float fv = g_gt[(dy * 8 + s) * 16 + m];  // uniform -> s_load
                    acc[s][0] = fmaf(fv, w[m + 0], acc[s][0]);
                    acc[s][1] = fmaf(fv, w[m + 1], acc[s][1]);
                    acc[s][2] = fmaf(fv, w[m + 2], acc[s][2]);
                    acc[s][3] = fmaf(fv, w[m + 3], acc[s][3]);
                }
            }
        }
    }

    float* obase = out + (size_t)bc * (NS * H * W) + (size_t)(i0 + it) * W + j0;
    #pragma unroll
    for (int s = 0; s < NS; ++s)
        *(float4*)(obase + (size_t)s * (H * W)) =
            make_float4(acc[s][0], acc[s][1], acc[s][2], acc[s][3]);
}

extern "C" void kernel_launch(void* const* d_in, const int* in_sizes, int n_in,
                              void* d_out, int out_size, void* d_ws, size_t ws_size,
                              hipStream_t stream) {
    const float* tens    = (const float*)d_in[0];
    const float* filters = (const float*)d_in[1];
    const int*   shifts  = (const int*)d_in[2];
    float* out = (float*)d_out;

    build_gt<<<(9 * 8 * 16 + 255) / 256, 256, 0, stream>>>(filters, shifts);
    shifted_conv_v3<<<256 * 16, 256, 0, stream>>>(tens, shifts, out);
}

// Round 8
// 176.447 us; speedup vs baseline: 2.3080x; 1.0097x over previous
//
#include <hip/hip_runtime.h>

#define H 128
#define W 128
#define NS 8
#define TR 16       // output rows per block
#define LR 24       // TR + 8 halo rows
#define LC 136      // W + 8 halo cols

// Zero-expanded tap table: Gt[dy][s][m] (m padded to 16) =
//   f[s][u][v] with u = dy-4+sy_s, v = m-4+sx_s, zero if u or v outside [0,5).
__device__ float g_gt[9 * 8 * 16];

__global__ __launch_bounds__(256) void build_gt(
    const float* __restrict__ filters,  // [8][5][5]
    const int*   __restrict__ shifts)   // [8][2]
{
    int t = blockIdx.x * 256 + threadIdx.x;
    if (t >= 9 * 8 * 16) return;
    int m  = t & 15;
    int s  = (t >> 4) & 7;
    int dy = t >> 7;
    float val = 0.f;
    if (m < 9) {
        int u = dy - 4 + shifts[2 * s];
        int v = m - 4 + shifts[2 * s + 1];
        if ((unsigned)u < 5u && (unsigned)v < 5u)
            val = filters[s * 25 + u * 5 + v];
    }
    g_gt[t] = val;
}

// out[bc, s, i, j] = sum_{u,v} f[s,u,v] * T[bc, i+u-sy_s, j+v-sx_s], zero-padded.
__global__ __launch_bounds__(512, 4) void shifted_conv_v4(
    const float* __restrict__ tens,     // [256][128][128]
    const int*   __restrict__ shifts,   // [8][2]
    float* __restrict__ out)            // [256][8][128][128]
{
    __shared__ float lds[LR][LC];   // 13056 B

    int blk  = blockIdx.x;
    int tile = blk & 7;             // 8 tiles of 16 rows
    int bc   = blk >> 3;
    int i0   = tile * TR;

    int tid = threadIdx.x;

    // ---- stage rows y in [i0-4, i0+20), cols x in [-4, 132) as float4 slots.
    // 24 rows x 34 float4-slots = 816 slots; c4==0 / c4==33 are halo zeros.
    const float* Timg = tens + (size_t)bc * (H * W);
    #pragma unroll
    for (int rep = 0; rep < 2; ++rep) {
        int slot = tid + rep * 512;
        if (slot < LR * 34) {
            unsigned r  = (unsigned)slot / 34u;   // 0..23
            int      c4 = slot - (int)r * 34;     // 0..33
            int y  = i0 - 4 + (int)r;
            int x4 = c4 - 1;
            float4 v = make_float4(0.f, 0.f, 0.f, 0.f);
            if ((unsigned)y < (unsigned)H && (unsigned)x4 < 32u)
                v = *((const float4*)(Timg + y * W) + x4);
            *(float4*)&lds[r][c4 * 4] = v;
        }
    }

    // Block-uniform shift rows, forced scalar.
    int sy[NS];
    #pragma unroll
    for (int s = 0; s < NS; ++s)
        sy[s] = __builtin_amdgcn_readfirstlane(shifts[2 * s]);

    __syncthreads();

    int it = tid >> 5;      // 0..15 (output row within tile)
    int jt = tid & 31;      // 32 threads per row
    int j0 = jt * 4;        // 4 consecutive outputs per thread

    float acc[NS][4];
    #pragma unroll
    for (int s = 0; s < NS; ++s)
        #pragma unroll
        for (int k = 0; k < 4; ++k) acc[s][k] = 0.f;

    const float* rp = &lds[it][j0];   // 16B-aligned (136%4==0, j0%4==0)

    #pragma unroll
    for (int dy = 0; dy < 9; ++dy) {
        // one window read per dy, shared by all 8 shifts
        float4 w0 = *(const float4*)(rp + dy * LC);
        float4 w1 = *(const float4*)(rp + dy * LC + 4);
        float4 w2 = *(const float4*)(rp + dy * LC + 8);
        float w[12] = {w0.x, w0.y, w0.z, w0.w,
                       w1.x, w1.y, w1.z, w1.w,
                       w2.x, w2.y, w2.z, w2.w};

        #pragma unroll
        for (int s = 0; s < NS; ++s) {
            // block-uniform: u = dy-4+sy_s must be a real filter row
            if ((unsigned)(dy - 4 + sy[s]) < 5u) {
                #pragma unroll
                for (int m = 0; m < 9; ++m) {
                    float fv = g_gt[(dy * 8 + s) * 16 + m];  // uniform -> s_load
                    acc[s][0] = fmaf(fv, w[m + 0], acc[s][0]);
                    acc[s][1] = fmaf(fv, w[m + 1], acc[s][1]);
                    acc[s][2] = fmaf(fv, w[m + 2], acc[s][2]);
                    acc[s][3] = fmaf(fv, w[m + 3], acc[s][3]);
                }
            }
        }
    }

    float* obase = out + (size_t)bc * (NS * H * W) + (size_t)(i0 + it) * W + j0;
    #pragma unroll
    for (int s = 0; s < NS; ++s)
        *(float4*)(obase + (size_t)s * (H * W)) =
            make_float4(acc[s][0], acc[s][1], acc[s][2], acc[s][3]);
}

extern "C" void kernel_launch(void* const* d_in, const int* in_sizes, int n_in,
                              void* d_out, int out_size, void* d_ws, size_t ws_size,
                              hipStream_t stream) {
    const float* tens    = (const float*)d_in[0];
    const float* filters = (const float*)d_in[1];
    const int*   shifts  = (const int*)d_in[2];
    float* out = (float*)d_out;

    build_gt<<<(9 * 8 * 16 + 255) / 256, 256, 0, stream>>>(filters, shifts);
    // 256 bc images x 8 row tiles, 512 threads
    shifted_conv_v4<<<256 * 8, 512, 0, stream>>>(tens, shifts, out);
}